// Round 5
// baseline (270.384 us; speedup 1.0000x reference)
//
#include <hip/hip_runtime.h>

// GGNN message passing, round 5: barrier-free MFMA main loop (round-4 structure)
// with the PROVEN round-3 one-hot expansion (round-4's __umul24 trick had a
// carry bug: z + (z<<14) propagates carries into bit 16).
//
//   adj in {0..3}. Planes: B0 = bit0(adj), B1 = bit1(adj), T = B0&B1.
//   P0 = B0@H, P1 = B1@H, PT = T@H, PA[e] = sum_j h[j][e]  (per batch)
//   m_in  = P0(M1-M0)^T + P1(M2-M0)^T + PT(M0-M1-M2+M3)^T + (bias + PA M0^T)
//   (out-direction: same with adj^T and Mout.)
//
// K1 pack_adj: streams adj (128 MB) once -> 2-bit row packs (adjP) + col packs
//   (adjPT), 8 MB each, in main-kernel tile order.
// K2 prep_h: h -> Hws bf16 H^T tiles [b][jc][u=j-octet][e] (4 MB) + PA.
// K3 prep_m: plane-combined M' bf16 + base vector (bias + PA M0^T).
// K4 ggnn_main: NO LDS / NO barriers in the K-loop (every fragment consumed
//   exactly once -> round-3 LDS staging bought only a 2-barrier convoy).
//   A: 4 broadcast uint4 per chunk; B: 4 coalesced b128/kstep from L2-hot Hws.
//   LDS only for per-wave epilogue S round-trip (27.6 KB, no barrier).

namespace {

typedef unsigned int  u32;
typedef unsigned short u16;
typedef __attribute__((ext_vector_type(8))) short bf16x8;
typedef __attribute__((ext_vector_type(4))) float f32x4;

constexpr int NN = 1024;
constexpr int ND = 64;

__device__ inline u16 f2bf(float x) {                  // f32 -> bf16 bits, RNE
    u32 u = __float_as_uint(x);
    return (u16)((u + 0x7FFFu + ((u >> 16) & 1u)) >> 16);
}
__device__ inline float bf2f(u16 x) { return __uint_as_float(((u32)x) << 16); }

// z has indicator bits at positions 0 and 2 (rest already masked off):
// -> u32 holding two bf16 values {0.0 or 1.0}. No carry path (bits isolated
// BEFORE the multiply). Verified in round 3.
__device__ inline u32 oh2(u32 z) {
    return ((z & 1u) | ((z & 4u) << 14)) * 0x3F80u;
}

// ---------------------------------------------------------------- K1: pack
// block = (b, It, Jt, s): adj rows It*256 + s*64 .. +64, cols Jt*256 .. +256.
// Emits: adjP[b][jc=Jt][it=It*4+s][u=seg][row]  (row-pack: edges along cols)
//        adjPT[b][jc=It][it=Jt*4+sc][u=s][il]   (col-pack: edges along rows)
__global__ __launch_bounds__(256) void pack_adj(
    const int* __restrict__ adj, u32* __restrict__ adjP, u32* __restrict__ adjPT)
{
    __shared__ u32 rp[64][16];   // [row][16 u32], u32 q = 16 cols
    const int t = threadIdx.x;
    const int bid = blockIdx.x;
    const int b = bid >> 6, It = (bid >> 4) & 3, Jt = (bid >> 2) & 3, s = bid & 3;
    const int* base = adj + ((size_t)b << 20) + (size_t)(It * 256 + s * 64) * NN + Jt * 256;

    const int row = t >> 2, seg = t & 3;
    const int* rptr = base + (size_t)row * NN + seg * 64;
    u32 w[4];
    #pragma unroll
    for (int q = 0; q < 4; ++q) {
        int4 v0 = *(const int4*)(rptr + q * 16 + 0);
        int4 v1 = *(const int4*)(rptr + q * 16 + 4);
        int4 v2 = *(const int4*)(rptr + q * 16 + 8);
        int4 v3 = *(const int4*)(rptr + q * 16 + 12);
        u32 u = (u32)(v0.x & 3) | ((u32)(v0.y & 3) << 2) | ((u32)(v0.z & 3) << 4) | ((u32)(v0.w & 3) << 6)
              | ((u32)(v1.x & 3) << 8) | ((u32)(v1.y & 3) << 10) | ((u32)(v1.z & 3) << 12) | ((u32)(v1.w & 3) << 14)
              | ((u32)(v2.x & 3) << 16) | ((u32)(v2.y & 3) << 18) | ((u32)(v2.z & 3) << 20) | ((u32)(v2.w & 3) << 22)
              | ((u32)(v3.x & 3) << 24) | ((u32)(v3.y & 3) << 26) | ((u32)(v3.z & 3) << 28) | ((u32)(v3.w & 3) << 30);
        w[q] = u;
    }
    u32* op = adjP + (((((size_t)b * 4 + Jt) * 16 + It * 4 + s) * 4 + seg) * 64 + row) * 4;
    *(uint4*)op = make_uint4(w[0], w[1], w[2], w[3]);
    *(uint4*)&rp[row][seg * 4] = make_uint4(w[0], w[1], w[2], w[3]);
    __syncthreads();

    const int sc = t >> 6, il = t & 63;
    const int cw = sc * 4 + (il >> 4);
    const int bp = (il & 15) * 2;
    u32 o[4];
    #pragma unroll
    for (int jj = 0; jj < 4; ++jj) {
        u32 acc = 0;
        #pragma unroll
        for (int k = 0; k < 16; ++k)
            acc |= ((rp[jj * 16 + k][cw] >> bp) & 3u) << (2 * k);
        o[jj] = acc;
    }
    u32* op2 = adjPT + (((((size_t)b * 4 + It) * 16 + Jt * 4 + sc) * 4 + s) * 64 + il) * 4;
    *(uint4*)op2 = make_uint4(o[0], o[1], o[2], o[3]);
}

// ---------------------------------------------------------------- K2: prep_h
__global__ __launch_bounds__(256) void prep_h(
    const float* __restrict__ h, u16* __restrict__ Hws, float* __restrict__ PA)
{
    __shared__ u16 hl[256][72];
    const int t = threadIdx.x;
    const int b = blockIdx.x >> 2, jc = blockIdx.x & 3;
    const float* hb = h + ((size_t)b * NN + jc * 256) * ND;
    #pragma unroll
    for (int k = 0; k < 16; ++k) {
        int j = k * 16 + (t >> 4);
        int e4 = (t & 15) * 4;
        float4 v = *(const float4*)(hb + (size_t)j * ND + e4);
        *(u32*)&hl[j][e4]     = (u32)f2bf(v.x) | ((u32)f2bf(v.y) << 16);
        *(u32*)&hl[j][e4 + 2] = (u32)f2bf(v.z) | ((u32)f2bf(v.w) << 16);
    }
    __syncthreads();
    u16* ob = Hws + (size_t)(b * 4 + jc) * 2048 * 8;
    const int e = t & 63;
    float psum = 0.f;
    #pragma unroll
    for (int k = 0; k < 8; ++k) {
        int u = k * 4 + (t >> 6);
        u16 x0 = hl[u * 8 + 0][e], x1 = hl[u * 8 + 1][e], x2 = hl[u * 8 + 2][e], x3 = hl[u * 8 + 3][e];
        u16 x4 = hl[u * 8 + 4][e], x5 = hl[u * 8 + 5][e], x6 = hl[u * 8 + 6][e], x7 = hl[u * 8 + 7][e];
        psum += bf2f(x0) + bf2f(x1) + bf2f(x2) + bf2f(x3) + bf2f(x4) + bf2f(x5) + bf2f(x6) + bf2f(x7);
        u32 p0 = (u32)x0 | ((u32)x1 << 16), p1 = (u32)x2 | ((u32)x3 << 16);
        u32 p2 = (u32)x4 | ((u32)x5 << 16), p3 = (u32)x6 | ((u32)x7 << 16);
        *(uint4*)(ob + (size_t)(u * 64 + e) * 8) = make_uint4(p0, p1, p2, p3);
    }
    atomicAdd(&PA[b * 64 + e], psum);
}

// ---------------------------------------------------------------- K3: prep_m
__global__ __launch_bounds__(256) void prep_m(
    const float* __restrict__ Min, const float* __restrict__ Mout,
    const float* __restrict__ bias, const float* __restrict__ PA,
    u16* __restrict__ Mws, float* __restrict__ basews)
{
    const int t = threadIdx.x, bb = blockIdx.x;
    if (bb == 0) {
        for (int i = t; i < 2 * 4096; i += 256) {
            const float* M = (i < 4096) ? Min : Mout;
            int idx = i & 4095;
            float m0 = M[idx], m1 = M[4096 + idx], m2 = M[8192 + idx], m3 = M[12288 + idx];
            u16* o = Mws + (size_t)(i >> 12) * 3 * 4096;
            o[idx]        = f2bf(m1 - m0);
            o[4096 + idx] = f2bf(m2 - m0);
            o[8192 + idx] = f2bf(m0 - m1 - m2 + m3);
        }
    }
    if (t < 128) {
        int d = t & 63, dir = t >> 6;
        const float* M0 = (dir ? Mout : Min) + d * 64;
        float s = bias[dir * 64 + d];
        #pragma unroll 8
        for (int e = 0; e < 64; ++e) s += PA[bb * 64 + e] * M0[e];
        basews[(bb * 2 + dir) * 64 + d] = s;
    }
}

// ---------------------------------------------------------------- K4: main
__global__ __launch_bounds__(256) void ggnn_main(
    const u32* __restrict__ adjP, const u32* __restrict__ adjPT,
    const u16* __restrict__ Hws, const u16* __restrict__ Mws,
    const float* __restrict__ basews, float* __restrict__ out)
{
    __shared__ u16 Sb[12][16][72];   // per-wave-exclusive epilogue slots, 27.6 KB

    const int t = threadIdx.x;
    const int w = t >> 6;
    const int ln = t & 15, qd = (t & 63) >> 4, qd2 = qd >> 1;
    const int shamt = (qd & 1) * 16;
    const int bid = blockIdx.x;
    const int dir = bid >> 9;
    const int b = (bid >> 4) & 31, it = bid & 15;

    const u32* Adir = dir ? adjPT : adjP;
    f32x4 acc[3][4];
    #pragma unroll
    for (int p = 0; p < 3; ++p)
        #pragma unroll
        for (int nt = 0; nt < 4; ++nt) acc[p][nt] = (f32x4){0.f, 0.f, 0.f, 0.f};

    for (int jc = 0; jc < 4; ++jc) {
        const u32* at = Adir + (size_t)((b * 4 + jc) * 16 + it) * 1024;
        const u16* ht = Hws + (size_t)(b * 4 + jc) * 16384;

        // A-words for the whole 256-j chunk: 4 broadcast uint4 per lane
        uint4 Ar[4];
        #pragma unroll
        for (int u = 0; u < 4; ++u)
            Ar[u] = *(const uint4*)(at + (u * 64 + w * 16 + ln) * 4);

        #pragma unroll
        for (int ks = 0; ks < 8; ++ks) {
            // B-fragments straight from global (L2-hot tile, coalesced b128)
            bf16x8 bf[4];
            #pragma unroll
            for (int nt = 0; nt < 4; ++nt)
                bf[nt] = *(const bf16x8*)(ht + (size_t)((ks * 4 + qd) * 64 + nt * 16 + ln) * 8);

            uint4 Q = Ar[ks >> 1];
            u32 a = (ks & 1) ? (qd2 ? Q.w : Q.z) : (qd2 ? Q.y : Q.x);
            u32 f = (a >> shamt) & 0xFFFFu;
            u32 x0 = f & 0x5555u;            // bit0 plane (classes 1,3)
            u32 x1 = (f >> 1) & 0x5555u;     // bit1 plane (classes 2,3)
            u32 xt = x0 & x1;                // class 3

            union { u32 u[4]; bf16x8 v; } A0, A1, AT;
            #pragma unroll
            for (int wd = 0; wd < 4; ++wd) {
                A0.u[wd] = oh2(x0 >> (4 * wd));
                A1.u[wd] = oh2(x1 >> (4 * wd));
                AT.u[wd] = oh2(xt >> (4 * wd));
            }
            #pragma unroll
            for (int nt = 0; nt < 4; ++nt) {
                acc[0][nt] = __builtin_amdgcn_mfma_f32_16x16x32_bf16(A0.v, bf[nt], acc[0][nt], 0, 0, 0);
                acc[1][nt] = __builtin_amdgcn_mfma_f32_16x16x32_bf16(A1.v, bf[nt], acc[1][nt], 0, 0, 0);
                acc[2][nt] = __builtin_amdgcn_mfma_f32_16x16x32_bf16(AT.v, bf[nt], acc[2][nt], 0, 0, 0);
            }
        }
    }

    // P (C-layout regs) -> LDS bf16, per-wave slots; no barrier needed
    #pragma unroll
    for (int p = 0; p < 3; ++p)
        #pragma unroll
        for (int nt = 0; nt < 4; ++nt)
            #pragma unroll
            for (int r = 0; r < 4; ++r)
                Sb[w * 3 + p][qd * 4 + r][nt * 16 + ln] = f2bf(acc[p][nt][r]);

    const float* bv = basews + (b * 2 + dir) * 64;
    f32x4 acc2[4];
    #pragma unroll
    for (int dt = 0; dt < 4; ++dt) {
        float v = bv[dt * 16 + ln];
        acc2[dt] = (f32x4){v, v, v, v};
    }
    const u16* Mb = Mws + (size_t)dir * 3 * 4096;
    #pragma unroll
    for (int p = 0; p < 3; ++p) {
        #pragma unroll
        for (int ks2 = 0; ks2 < 2; ++ks2) {
            bf16x8 af = *(const bf16x8*)&Sb[w * 3 + p][ln][ks2 * 32 + qd * 8];
            #pragma unroll
            for (int dt = 0; dt < 4; ++dt) {
                bf16x8 mf = *(const bf16x8*)(Mb + (size_t)(p * 64 + dt * 16 + ln) * 64
                                             + ks2 * 32 + qd * 8);
                acc2[dt] = __builtin_amdgcn_mfma_f32_16x16x32_bf16(af, mf, acc2[dt], 0, 0, 0);
            }
        }
    }
    #pragma unroll
    for (int dt = 0; dt < 4; ++dt)
        #pragma unroll
        for (int r = 0; r < 4; ++r)
            out[((size_t)b * NN + it * 64 + w * 16 + qd * 4 + r) * 128
                + dir * 64 + dt * 16 + ln] = acc2[dt][r];
}

} // namespace

extern "C" void kernel_launch(void* const* d_in, const int* in_sizes, int n_in,
                              void* d_out, int out_size, void* d_ws, size_t ws_size,
                              hipStream_t stream) {
    (void)in_sizes; (void)n_in; (void)out_size; (void)ws_size;
    const float* h    = (const float*)d_in[0];   // [32,1024,64] f32
    const int*   adj  = (const int*)d_in[1];     // [32,1024,1024] i32
    const float* Min  = (const float*)d_in[2];   // [4,64,64] f32
    const float* Mout = (const float*)d_in[3];   // [4,64,64] f32
    const float* bias = (const float*)d_in[4];   // [128] f32
    float* out = (float*)d_out;                  // [32,1024,128] f32

    char* ws = (char*)d_ws;
    u32* adjP   = (u32*)(ws + 0);              // 8 MB
    u32* adjPT  = (u32*)(ws + 8388608);        // 8 MB
    u16* Hws    = (u16*)(ws + 16777216);       // 4 MB
    float* PA   = (float*)(ws + 20971520);     // 8 KB
    u16* Mws    = (u16*)(ws + 20979712);       // 48 KB
    float* basews = (float*)(ws + 21028864);   // 16 KB

    hipMemsetAsync(PA, 0, 32 * 64 * sizeof(float), stream);
    pack_adj<<<2048, 256, 0, stream>>>(adj, adjP, adjPT);
    prep_h<<<128, 256, 0, stream>>>(h, Hws, PA);
    prep_m<<<32, 256, 0, stream>>>(Min, Mout, bias, PA, Mws, basews);
    ggnn_main<<<1024, 256, 0, stream>>>(adjP, adjPT, Hws, Mws, basews, out);
}